// Round 5
// baseline (5187.638 us; speedup 1.0000x reference)
//
#include <hip/hip_runtime.h>
#include <math.h>

#define N_EL    16
#define N_NUC   4
#define N_FEATS 32
#define HIDDEN  64
#define G       8            // threads per batch element
#define TB      32           // batch elements per block
#define BLOCK   256
#define H1LD    68           // h1 LDS leading dim (floats): 16B-aligned, bank-spread

// triu_indices(16, 1)
__constant__ unsigned char c_I[120] = {
    0,0,0,0,0,0,0,0,0,0,0,0,0,0,0,
    1,1,1,1,1,1,1,1,1,1,1,1,1,1,
    2,2,2,2,2,2,2,2,2,2,2,2,2,
    3,3,3,3,3,3,3,3,3,3,3,3,
    4,4,4,4,4,4,4,4,4,4,4,
    5,5,5,5,5,5,5,5,5,5,
    6,6,6,6,6,6,6,6,6,
    7,7,7,7,7,7,7,7,
    8,8,8,8,8,8,8,
    9,9,9,9,9,9,
    10,10,10,10,10,
    11,11,11,11,
    12,12,12,
    13,13,
    14
};
__constant__ unsigned char c_J[120] = {
    1,2,3,4,5,6,7,8,9,10,11,12,13,14,15,
    2,3,4,5,6,7,8,9,10,11,12,13,14,15,
    3,4,5,6,7,8,9,10,11,12,13,14,15,
    4,5,6,7,8,9,10,11,12,13,14,15,
    5,6,7,8,9,10,11,12,13,14,15,
    6,7,8,9,10,11,12,13,14,15,
    7,8,9,10,11,12,13,14,15,
    8,9,10,11,12,13,14,15,
    9,10,11,12,13,14,15,
    10,11,12,13,14,15,
    11,12,13,14,15,
    12,13,14,15,
    13,14,15,
    14,15,
    15
};

// shifted softplus: softplus(x) - log(2), numerically stable
__device__ __forceinline__ float ssp(float x) {
    float a = fabsf(x);
    return fmaxf(x, 0.0f) + log1pf(__expf(-a)) - 0.69314718056f;
}

// sum over the 8 g-lanes (low 3 lane bits)
__device__ __forceinline__ float redg(float v) {
    v += __shfl_xor(v, 1);
    v += __shfl_xor(v, 2);
    v += __shfl_xor(v, 4);
    return v;
}

// One output-half pass: accumulate h1 columns [PASS_ID*32, PASS_ID*32+32)
// over all 184 pairs into 8 named float4s (32 VGPRs live -> fits the
// 64-VGPR budget the allocator insists on; R1-R4 showed both arrays and
// 64 named floats spill at ~5200us). Reduced+ssp'd result goes to LDS.
template<int PASS_ID>
__device__ __forceinline__ void wf_pass(const float* __restrict__ myrs,
                                        const float4* __restrict__ W1v,
                                        const float* __restrict__ coords,
                                        const float4 ch,
                                        const float2* __restrict__ lds_ms,
                                        const float4* __restrict__ b1v,
                                        float* __restrict__ h1_dst,
                                        int g, float& asy)
{
    constexpr int COL4 = PASS_ID * 8;   // float4 column offset into a W1 row
    const float4 zero4 = make_float4(0.f, 0.f, 0.f, 0.f);
    float4 A0 = zero4, A1 = zero4, A2 = zero4, A3 = zero4,
           A4 = zero4, A5 = zero4, A6 = zero4, A7 = zero4;

#define FMA4(n) { const float4 w = r[n]; \
    A##n.x = fmaf(x, w.x, A##n.x); \
    A##n.y = fmaf(x, w.y, A##n.y); \
    A##n.z = fmaf(x, w.z, A##n.z); \
    A##n.w = fmaf(x, w.w, A##n.w); }

#define FEATS(dv, rowbase) { \
    const float4* __restrict__ row = (rowbase); \
    for (int f = 0; f < N_FEATS; ++f) { \
        const float2 ms = lds_ms[f]; \
        const float t = fmaf((dv), ms.y, -ms.x); \
        const float x = __expf(-(t * t)); \
        const float4* __restrict__ r = row + (f << 4); \
        FMA4(0) FMA4(1) FMA4(2) FMA4(3) \
        FMA4(4) FMA4(5) FMA4(6) FMA4(7) \
    } }

    // electron-nucleus pairs: p = g + 8*i
    for (int i = 0; i < 8; ++i) {
        const int p = g + 8 * i;
        const int e = p >> 2, n = p & 3;
        const float dx = myrs[e * 3 + 0] - coords[n * 3 + 0];
        const float dy = myrs[e * 3 + 1] - coords[n * 3 + 1];
        const float dz = myrs[e * 3 + 2] - coords[n * 3 + 2];
        const float d  = sqrtf(dx * dx + dy * dy + dz * dz);
        if (PASS_ID == 0) {
            const float Z = (n < 2) ? ((n == 0) ? ch.x : ch.y)
                                    : ((n == 2) ? ch.z : ch.w);
            asy += (Z * d + d * d) / (1.0f + d);   // decay = sqrt(2*0.5) = 1
        }
        FEATS(d, W1v + ((size_t)p << 9) + COL4);
    }
    // electron-electron pairs: q = g + 8*i
    for (int i = 0; i < 15; ++i) {
        const int q  = g + 8 * i;
        const int ei = 3 * (int)c_I[q], ej = 3 * (int)c_J[q];
        const float dx = myrs[ei + 0] - myrs[ej + 0];
        const float dy = myrs[ei + 1] - myrs[ej + 1];
        const float dz = myrs[ei + 2] - myrs[ej + 2];
        const float d  = sqrtf(dx * dx + dy * dy + dz * dz);
        FEATS(d, W1v + ((size_t)(64 + q) << 9) + COL4);
    }

    float4* __restrict__ dst = (float4*)h1_dst + COL4;
#define REDST(n) { const float4 bb = b1v[COL4 + n]; float4 hv; \
    hv.x = ssp(redg(A##n.x) + bb.x); \
    hv.y = ssp(redg(A##n.y) + bb.y); \
    hv.z = ssp(redg(A##n.z) + bb.z); \
    hv.w = ssp(redg(A##n.w) + bb.w); \
    if (g == 0) dst[n] = hv; }
    REDST(0) REDST(1) REDST(2) REDST(3)
    REDST(4) REDST(5) REDST(6) REDST(7)
#undef REDST
#undef FEATS
#undef FMA4
}

__global__ __launch_bounds__(BLOCK)
void wfnet_kernel(const float* __restrict__ rs,
                  const float* __restrict__ coords,
                  const float* __restrict__ charges,
                  const float* __restrict__ W1,
                  const float* __restrict__ b1,
                  const float* __restrict__ W2,
                  const float* __restrict__ b2,
                  const float* __restrict__ W3,
                  const float* __restrict__ b3,
                  float* __restrict__ out)
{
    __shared__ float  lds_rs[TB * N_EL * 3];   // 6 KB
    __shared__ float2 lds_ms[N_FEATS];         // {mu/sigma, 1/sigma}
    __shared__ float  lds_h1[TB * H1LD];       // 8.5 KB, padded stride

    const int tid     = threadIdx.x;
    const int b_local = tid >> 3;              // 0..31
    const int g       = tid & 7;               // 0..7
    const int b       = blockIdx.x * TB + b_local;

    // stage this block's rs rows (coalesced)
    {
        const float* rs_blk = rs + (size_t)blockIdx.x * (TB * N_EL * 3);
        for (int k = tid; k < TB * N_EL * 3; k += BLOCK) lds_rs[k] = rs_blk[k];
    }
    // per-feature constants once per block
    if (tid < N_FEATS) {
        const float qs = (float)tid * (1.0f / 31.0f);
        const float mu = 10.0f * qs * qs;
        const float sg = (1.0f + 10.0f * qs) * (1.0f / 7.0f);
        const float s  = 1.0f / sg;
        lds_ms[tid] = make_float2(mu * s, s);
    }
    __syncthreads();

    const float* myrs = lds_rs + b_local * (N_EL * 3);
    const float4* __restrict__ W1v = (const float4*)W1;
    const float4* __restrict__ b1v = (const float4*)b1;
    const float4 ch = *(const float4*)charges;

    float asy = 0.0f;
    float* h1me = lds_h1 + b_local * H1LD;
    wf_pass<0>(myrs, W1v, coords, ch, lds_ms, b1v, h1me, g, asy);
    wf_pass<1>(myrs, W1v, coords, ch, lds_ms, b1v, h1me, g, asy);
    asy = redg(asy);
    __syncthreads();   // h1 visible block-wide (writer/readers same wave, but be safe)

    // ---- layer 2: lane g computes outputs g*8 .. g*8+7; h1 read from LDS
    // (runtime-indexed loop is fine for LDS -- only register arrays trap) ----
    const float4* __restrict__ W2v = (const float4*)W2;
    const float4* __restrict__ b2v = (const float4*)b2;
    const int wbi = g * 2;
    const float4 b2a = b2v[wbi], b2b = b2v[wbi + 1];
    float s0 = b2a.x, s1 = b2a.y, s2 = b2a.z, s3 = b2a.w;
    float s4 = b2b.x, s5 = b2b.y, s6 = b2b.z, s7 = b2b.w;

    const float* __restrict__ h1row = lds_h1 + b_local * H1LD;
    for (int k = 0; k < HIDDEN; ++k) {
        const float hk  = h1row[k];
        const float4 wa = W2v[k * 16 + wbi];
        const float4 wb = W2v[k * 16 + wbi + 1];
        s0 = fmaf(hk, wa.x, s0); s1 = fmaf(hk, wa.y, s1);
        s2 = fmaf(hk, wa.z, s2); s3 = fmaf(hk, wa.w, s3);
        s4 = fmaf(hk, wb.x, s4); s5 = fmaf(hk, wb.y, s5);
        s6 = fmaf(hk, wb.z, s6); s7 = fmaf(hk, wb.w, s7);
    }

    // ---- layer 3 partial dot over this lane's 8 outputs ----
    const float4* __restrict__ W3v = (const float4*)W3;
    const float4 w3a = W3v[wbi], w3b = W3v[wbi + 1];
    float part = ssp(s0) * w3a.x + ssp(s1) * w3a.y
               + ssp(s2) * w3a.z + ssp(s3) * w3a.w
               + ssp(s4) * w3b.x + ssp(s5) * w3b.y
               + ssp(s6) * w3b.z + ssp(s7) * w3b.w;
    part = redg(part);

    if (g == 0) {
        const float ys = part + b3[0];
        out[b] = __expf(ys) * __expf(-asy);
    }
}

extern "C" void kernel_launch(void* const* d_in, const int* in_sizes, int n_in,
                              void* d_out, int out_size, void* d_ws, size_t ws_size,
                              hipStream_t stream) {
    const float* rs      = (const float*)d_in[0];
    const float* coords  = (const float*)d_in[1];
    const float* charges = (const float*)d_in[2];
    const float* W1      = (const float*)d_in[3];
    const float* b1      = (const float*)d_in[4];
    const float* W2      = (const float*)d_in[5];
    const float* b2      = (const float*)d_in[6];
    const float* W3      = (const float*)d_in[7];
    const float* b3      = (const float*)d_in[8];
    float* out = (float*)d_out;

    const int batch = in_sizes[0] / (N_EL * 3);   // 32768
    const int grid  = batch / TB;                 // 1024 blocks

    wfnet_kernel<<<grid, BLOCK, 0, stream>>>(rs, coords, charges,
                                             W1, b1, W2, b2, W3, b3, out);
}

// Round 6
// 621.489 us; speedup vs baseline: 8.3471x; 8.3471x over previous
//
#include <hip/hip_runtime.h>
#include <math.h>

#define N_EL    16
#define N_NUC   4
#define N_FEATS 32
#define HIDDEN  64
#define TB      32           // batch elements per block
#define BLOCK   256
#define H1LD    68           // h1 LDS leading dim (floats), bank-spread
#define PT      2            // pairs per W1 LDS tile (16 KB)
#define NT_NUC  32           // el-nuc tiles (pairs 0..63)
#define NT_EL   60           // el-el tiles (pairs 64..183)

// triu_indices(16, 1)
__constant__ unsigned char c_I[120] = {
    0,0,0,0,0,0,0,0,0,0,0,0,0,0,0,
    1,1,1,1,1,1,1,1,1,1,1,1,1,1,
    2,2,2,2,2,2,2,2,2,2,2,2,2,
    3,3,3,3,3,3,3,3,3,3,3,3,
    4,4,4,4,4,4,4,4,4,4,4,
    5,5,5,5,5,5,5,5,5,5,
    6,6,6,6,6,6,6,6,6,
    7,7,7,7,7,7,7,7,
    8,8,8,8,8,8,8,
    9,9,9,9,9,9,
    10,10,10,10,10,
    11,11,11,11,
    12,12,12,
    13,13,
    14
};
__constant__ unsigned char c_J[120] = {
    1,2,3,4,5,6,7,8,9,10,11,12,13,14,15,
    2,3,4,5,6,7,8,9,10,11,12,13,14,15,
    3,4,5,6,7,8,9,10,11,12,13,14,15,
    4,5,6,7,8,9,10,11,12,13,14,15,
    5,6,7,8,9,10,11,12,13,14,15,
    6,7,8,9,10,11,12,13,14,15,
    7,8,9,10,11,12,13,14,15,
    8,9,10,11,12,13,14,15,
    9,10,11,12,13,14,15,
    10,11,12,13,14,15,
    11,12,13,14,15,
    12,13,14,15,
    13,14,15,
    14,15,
    15
};

// shifted softplus: softplus(x) - log(2), numerically stable
__device__ __forceinline__ float ssp(float x) {
    float a = fabsf(x);
    return fmaxf(x, 0.0f) + log1pf(__expf(-a)) - 0.69314718056f;
}

// sum over the 8 g-lanes (low 3 lane bits)
__device__ __forceinline__ float redg(float v) {
    v += __shfl_xor(v, 1);
    v += __shfl_xor(v, 2);
    v += __shfl_xor(v, 4);
    return v;
}

// One pair's 32 features: x = exp(-((d-mu_f)/sg_f)^2), acc += x * W1_row.
// f is fully unrolled so mu/1-over-sigma fold to compile-time constants.
// lw is pre-offset by g*2 float4s; (pf+f)*16 is a constant ds offset.
// R1-R5 lesson: accumulators are NAMED floats (never an indexable array),
// and the live set (~50 regs) fits the 64-VGPR budget the allocator picks.
__device__ __forceinline__ void pair32(float dv, const float4* __restrict__ lw,
                                       int pf,
                                       float& a0, float& a1, float& a2, float& a3,
                                       float& a4, float& a5, float& a6, float& a7)
{
#pragma unroll
    for (int f = 0; f < N_FEATS; ++f) {
        const float qs = (float)f * (1.0f / 31.0f);
        const float mu = 10.0f * qs * qs;
        const float is = 7.0f / (1.0f + 10.0f * qs);   // 1/sigma, const-folded
        const float t  = (dv - mu) * is;
        const float x  = __expf(-(t * t));
        const float4 wa = lw[(pf + f) * 16];
        const float4 wb = lw[(pf + f) * 16 + 1];
        a0 = fmaf(x, wa.x, a0); a1 = fmaf(x, wa.y, a1);
        a2 = fmaf(x, wa.z, a2); a3 = fmaf(x, wa.w, a3);
        a4 = fmaf(x, wb.x, a4); a5 = fmaf(x, wb.y, a5);
        a6 = fmaf(x, wb.z, a6); a7 = fmaf(x, wb.w, a7);
    }
}

__global__ __launch_bounds__(BLOCK)
void wfnet_kernel(const float* __restrict__ rs,
                  const float* __restrict__ coords,
                  const float* __restrict__ charges,
                  const float* __restrict__ W1,
                  const float* __restrict__ b1,
                  const float* __restrict__ W2,
                  const float* __restrict__ b2,
                  const float* __restrict__ W3,
                  const float* __restrict__ b3,
                  float* __restrict__ out)
{
    __shared__ float lds_rs[TB * N_EL * 3];            // 6 KB
    __shared__ float lds_w1[PT * N_FEATS * HIDDEN];    // 16 KB W1 tile
    __shared__ float lds_h1[TB * H1LD];                // 8.5 KB

    const int tid     = threadIdx.x;
    const int b_local = tid >> 3;              // 0..31 (element in block)
    const int g       = tid & 7;               // 0..7  (column chunk)
    const int b       = blockIdx.x * TB + b_local;

    // stage this block's rs rows (coalesced)
    {
        const float* rs_blk = rs + (size_t)blockIdx.x * (TB * N_EL * 3);
        for (int k = tid; k < TB * N_EL * 3; k += BLOCK) lds_rs[k] = rs_blk[k];
    }
    __syncthreads();

    const float* myrs = lds_rs + b_local * (N_EL * 3);
    const float4* __restrict__ W1v4 = (const float4*)W1;
    const float4* __restrict__ lw   = ((const float4*)lds_w1) + g * 2;
    const float4 ch = *(const float4*)charges;

    float a0 = 0.f, a1 = 0.f, a2 = 0.f, a3 = 0.f,
          a4 = 0.f, a5 = 0.f, a6 = 0.f, a7 = 0.f;
    float asy = 0.0f;   // full per-element asymptote sum (no reduction needed)

    // ---- electron-nucleus tiles: pairs p0=2t, 2t+1 (t = 0..31) ----
    for (int t = 0; t < NT_NUC; ++t) {
        const int p0 = 2 * t;
        __syncthreads();   // previous tile fully consumed
        {
            const float4* src = W1v4 + (size_t)p0 * 512 + tid;
            float4* dst = (float4*)lds_w1;
            const float4 v0 = src[0], v1 = src[256], v2 = src[512], v3 = src[768];
            dst[tid]       = v0;  dst[tid + 256] = v1;
            dst[tid + 512] = v2;  dst[tid + 768] = v3;
        }
        float d0, d1;
        {
            const int e = p0 >> 2, n = p0 & 3;
            const float dx = myrs[e * 3 + 0] - coords[n * 3 + 0];
            const float dy = myrs[e * 3 + 1] - coords[n * 3 + 1];
            const float dz = myrs[e * 3 + 2] - coords[n * 3 + 2];
            d0 = sqrtf(dx * dx + dy * dy + dz * dz);
            const float Z = (n < 2) ? ((n == 0) ? ch.x : ch.y)
                                    : ((n == 2) ? ch.z : ch.w);
            asy += (Z * d0 + d0 * d0) / (1.0f + d0);   // decay = sqrt(2*0.5) = 1
        }
        {
            const int p1 = p0 + 1;
            const int e = p1 >> 2, n = p1 & 3;
            const float dx = myrs[e * 3 + 0] - coords[n * 3 + 0];
            const float dy = myrs[e * 3 + 1] - coords[n * 3 + 1];
            const float dz = myrs[e * 3 + 2] - coords[n * 3 + 2];
            d1 = sqrtf(dx * dx + dy * dy + dz * dz);
            const float Z = (n < 2) ? ((n == 0) ? ch.x : ch.y)
                                    : ((n == 2) ? ch.z : ch.w);
            asy += (Z * d1 + d1 * d1) / (1.0f + d1);
        }
        __syncthreads();   // tile visible
        pair32(d0, lw, 0,           a0,a1,a2,a3,a4,a5,a6,a7);
        pair32(d1, lw, N_FEATS,     a0,a1,a2,a3,a4,a5,a6,a7);
    }

    // ---- electron-electron tiles: pairs 64+2t, 64+2t+1 (t = 0..59) ----
    for (int t = 0; t < NT_EL; ++t) {
        const int q0 = 2 * t;
        __syncthreads();
        {
            const float4* src = W1v4 + (size_t)(64 + q0) * 512 + tid;
            float4* dst = (float4*)lds_w1;
            const float4 v0 = src[0], v1 = src[256], v2 = src[512], v3 = src[768];
            dst[tid]       = v0;  dst[tid + 256] = v1;
            dst[tid + 512] = v2;  dst[tid + 768] = v3;
        }
        float d0, d1;
        {
            const int ei = 3 * (int)c_I[q0], ej = 3 * (int)c_J[q0];
            const float dx = myrs[ei + 0] - myrs[ej + 0];
            const float dy = myrs[ei + 1] - myrs[ej + 1];
            const float dz = myrs[ei + 2] - myrs[ej + 2];
            d0 = sqrtf(dx * dx + dy * dy + dz * dz);
        }
        {
            const int ei = 3 * (int)c_I[q0 + 1], ej = 3 * (int)c_J[q0 + 1];
            const float dx = myrs[ei + 0] - myrs[ej + 0];
            const float dy = myrs[ei + 1] - myrs[ej + 1];
            const float dz = myrs[ei + 2] - myrs[ej + 2];
            d1 = sqrtf(dx * dx + dy * dy + dz * dz);
        }
        __syncthreads();
        pair32(d0, lw, 0,           a0,a1,a2,a3,a4,a5,a6,a7);
        pair32(d1, lw, N_FEATS,     a0,a1,a2,a3,a4,a5,a6,a7);
    }

    // ---- h1 = ssp(acc + b1) for this lane's 8 columns -> LDS ----
    const float4* __restrict__ b1v = (const float4*)b1;
    const int wbi = g * 2;
    {
        const float4 bb0 = b1v[wbi], bb1 = b1v[wbi + 1];
        float4 h1a, h1b;
        h1a.x = ssp(a0 + bb0.x); h1a.y = ssp(a1 + bb0.y);
        h1a.z = ssp(a2 + bb0.z); h1a.w = ssp(a3 + bb0.w);
        h1b.x = ssp(a4 + bb1.x); h1b.y = ssp(a5 + bb1.y);
        h1b.z = ssp(a6 + bb1.z); h1b.w = ssp(a7 + bb1.w);
        float4* h1w = (float4*)(lds_h1 + b_local * H1LD + g * 8);
        h1w[0] = h1a; h1w[1] = h1b;
    }
    __syncthreads();

    // ---- layer 2: lane g computes outputs g*8 .. g*8+7; h1 from LDS ----
    const float4* __restrict__ W2v = (const float4*)W2;
    const float4* __restrict__ b2v = (const float4*)b2;
    const float4 b2a = b2v[wbi], b2b = b2v[wbi + 1];
    float s0 = b2a.x, s1 = b2a.y, s2 = b2a.z, s3 = b2a.w;
    float s4 = b2b.x, s5 = b2b.y, s6 = b2b.z, s7 = b2b.w;

    const float* __restrict__ h1row = lds_h1 + b_local * H1LD;
    for (int k = 0; k < HIDDEN; ++k) {
        const float hk  = h1row[k];
        const float4 wa = W2v[k * 16 + wbi];
        const float4 wb = W2v[k * 16 + wbi + 1];
        s0 = fmaf(hk, wa.x, s0); s1 = fmaf(hk, wa.y, s1);
        s2 = fmaf(hk, wa.z, s2); s3 = fmaf(hk, wa.w, s3);
        s4 = fmaf(hk, wb.x, s4); s5 = fmaf(hk, wb.y, s5);
        s6 = fmaf(hk, wb.z, s6); s7 = fmaf(hk, wb.w, s7);
    }

    // ---- layer 3 partial dot over this lane's 8 outputs ----
    const float4* __restrict__ W3v = (const float4*)W3;
    const float4 w3a = W3v[wbi], w3b = W3v[wbi + 1];
    float part = ssp(s0) * w3a.x + ssp(s1) * w3a.y
               + ssp(s2) * w3a.z + ssp(s3) * w3a.w
               + ssp(s4) * w3b.x + ssp(s5) * w3b.y
               + ssp(s6) * w3b.z + ssp(s7) * w3b.w;
    part = redg(part);

    if (g == 0) {
        const float ys = part + b3[0];
        out[b] = __expf(ys) * __expf(-asy);
    }
}

extern "C" void kernel_launch(void* const* d_in, const int* in_sizes, int n_in,
                              void* d_out, int out_size, void* d_ws, size_t ws_size,
                              hipStream_t stream) {
    const float* rs      = (const float*)d_in[0];
    const float* coords  = (const float*)d_in[1];
    const float* charges = (const float*)d_in[2];
    const float* W1      = (const float*)d_in[3];
    const float* b1      = (const float*)d_in[4];
    const float* W2      = (const float*)d_in[5];
    const float* b2      = (const float*)d_in[6];
    const float* W3      = (const float*)d_in[7];
    const float* b3      = (const float*)d_in[8];
    float* out = (float*)d_out;

    const int batch = in_sizes[0] / (N_EL * 3);   // 32768
    const int grid  = batch / TB;                 // 1024 blocks

    wfnet_kernel<<<grid, BLOCK, 0, stream>>>(rs, coords, charges,
                                             W1, b1, W2, b2, W3, b3, out);
}

// Round 7
// 226.038 us; speedup vs baseline: 22.9503x; 2.7495x over previous
//
#include <hip/hip_runtime.h>
#include <math.h>

#define N_EL    16
#define N_NUC   4
#define N_FEATS 32
#define N_PAIRS 184
#define HIDDEN  64
#define TB      32           // batch elements per block
#define BLOCK   256
#define DLD     185          // dist LDS stride (odd -> conflict-free column reads)
#define H1LD    68
#define NTILES  92           // K-tiles of 2 pairs each

typedef _Float16 half8  __attribute__((ext_vector_type(8)));
typedef float    floatx4 __attribute__((ext_vector_type(4)));

// triu_indices(16, 1)
__constant__ unsigned char c_I[120] = {
    0,0,0,0,0,0,0,0,0,0,0,0,0,0,0,
    1,1,1,1,1,1,1,1,1,1,1,1,1,1,
    2,2,2,2,2,2,2,2,2,2,2,2,2,
    3,3,3,3,3,3,3,3,3,3,3,3,
    4,4,4,4,4,4,4,4,4,4,4,
    5,5,5,5,5,5,5,5,5,5,
    6,6,6,6,6,6,6,6,6,
    7,7,7,7,7,7,7,7,
    8,8,8,8,8,8,8,
    9,9,9,9,9,9,
    10,10,10,10,10,
    11,11,11,11,
    12,12,12,
    13,13,
    14
};
__constant__ unsigned char c_J[120] = {
    1,2,3,4,5,6,7,8,9,10,11,12,13,14,15,
    2,3,4,5,6,7,8,9,10,11,12,13,14,15,
    3,4,5,6,7,8,9,10,11,12,13,14,15,
    4,5,6,7,8,9,10,11,12,13,14,15,
    5,6,7,8,9,10,11,12,13,14,15,
    6,7,8,9,10,11,12,13,14,15,
    7,8,9,10,11,12,13,14,15,
    8,9,10,11,12,13,14,15,
    9,10,11,12,13,14,15,
    10,11,12,13,14,15,
    11,12,13,14,15,
    12,13,14,15,
    13,14,15,
    14,15,
    15
};

__device__ __forceinline__ float ssp(float x) {
    float a = fabsf(x);
    return fmaxf(x, 0.0f) + log1pf(__expf(-a)) - 0.69314718056f;
}
__device__ __forceinline__ float redg(float v) {
    v += __shfl_xor(v, 1);
    v += __shfl_xor(v, 2);
    v += __shfl_xor(v, 4);
    return v;
}

// ---------------------------------------------------------------------------
// Prep: scramble W1 (fp32 [5888][64] row-major) into fp16 B-fragment lane
// order in d_ws. Chunk id = ((pair*4 + ntile)*64 + lane); chunk holds
// B[k=quad*8+j][n=ntile*16+(lane&15)] for j=0..7 (one ds_read_b128 per lane).
// ---------------------------------------------------------------------------
__global__ __launch_bounds__(256)
void prep_w1_kernel(const float* __restrict__ W1, half8* __restrict__ ws)
{
    const int gid   = blockIdx.x * 256 + threadIdx.x;   // 0..47103
    const int pair  = gid >> 8;
    const int ntile = (gid >> 6) & 3;
    const int lane  = gid & 63;
    const int quad  = lane >> 4;
    const int n15   = lane & 15;
    const float* src = W1 + (size_t)(pair * 32 + quad * 8) * 64 + ntile * 16 + n15;
    half8 h;
    h[0] = (_Float16)src[0 * 64]; h[1] = (_Float16)src[1 * 64];
    h[2] = (_Float16)src[2 * 64]; h[3] = (_Float16)src[3 * 64];
    h[4] = (_Float16)src[4 * 64]; h[5] = (_Float16)src[5 * 64];
    h[6] = (_Float16)src[6 * 64]; h[7] = (_Float16)src[7 * 64];
    ws[gid] = h;
}

// ---------------------------------------------------------------------------
// Main kernel. Block = 32 elements, 4 waves. Wave (mh = wave&1, ng = wave>>1)
// computes h1 tile [mh*16..+15] x [ng*32..+31] via MFMA 16x16x32_f16,
// K-slab = one pair (32 features). A-frag built in-register (zero exp
// redundancy); B-frags from LDS-staged pre-scrambled fp16 W1.
// ---------------------------------------------------------------------------
__global__ __launch_bounds__(BLOCK)
void wfnet_kernel(const float* __restrict__ rs,
                  const float* __restrict__ coords,
                  const float* __restrict__ charges,
                  const half8* __restrict__ ws,
                  const float* __restrict__ b1,
                  const float* __restrict__ W2,
                  const float* __restrict__ b2,
                  const float* __restrict__ W3,
                  const float* __restrict__ b3,
                  float* __restrict__ out)
{
    __shared__ __align__(16) _Float16 lds_w1[2 * 4 * 64 * 8]; // 8 KB tile (2 pairs)
    __shared__ float lds_dist[TB * DLD];                      // 23.1 KB
    __shared__ float lds_h1[TB * H1LD];                       // 8.5 KB

    const int tid  = threadIdx.x;
    const int wave = tid >> 6;
    const int lane = tid & 63;
    const int quad = lane >> 4;
    const int m    = lane & 15;
    const int mh   = wave & 1;
    const int ng   = wave >> 1;

    // ---- phase 1: stage rs into the w1-tile buffer (transient reuse) ----
    {
        float* lds_rs = (float*)lds_w1;
        const float* rs_blk = rs + (size_t)blockIdx.x * (TB * N_EL * 3);
        for (int k = tid; k < TB * N_EL * 3; k += BLOCK) lds_rs[k] = rs_blk[k];
    }
    __syncthreads();

    // ---- phase 2: all 184 distances per element -> lds_dist ----
    {
        const int bl = tid >> 3, g = tid & 7;
        const float* myrs = (const float*)lds_w1 + bl * (N_EL * 3);
        float* dst = lds_dist + bl * DLD;
        for (int i = 0; i < 8; ++i) {           // el-nuc pairs p = g+8i
            const int p = g + 8 * i;
            const int e = p >> 2, n = p & 3;
            const float dx = myrs[e * 3 + 0] - coords[n * 3 + 0];
            const float dy = myrs[e * 3 + 1] - coords[n * 3 + 1];
            const float dz = myrs[e * 3 + 2] - coords[n * 3 + 2];
            dst[p] = sqrtf(dx * dx + dy * dy + dz * dz);
        }
        for (int i = 0; i < 15; ++i) {          // el-el pairs 64 + (g+8i)
            const int q  = g + 8 * i;
            const int ei = 3 * (int)c_I[q], ej = 3 * (int)c_J[q];
            const float dx = myrs[ei + 0] - myrs[ej + 0];
            const float dy = myrs[ei + 1] - myrs[ej + 1];
            const float dz = myrs[ei + 2] - myrs[ej + 2];
            dst[64 + q] = sqrtf(dx * dx + dy * dy + dz * dz);
        }
    }
    // (loop-top barrier below makes dists visible and rs-reads complete)

    // per-lane feature constants: f = quad*8 + j
    // x = exp(-((d-mu)/sg)^2) = 2^(-(d*C1 + C0)^2), C1=is*S, C0=-mu*is*S,
    // S = sqrt(log2 e)
#define MKC(j) float C0_##j, C1_##j; { \
    const float fq = (float)(quad * 8 + j) * (1.0f / 31.0f); \
    const float mu = 10.0f * fq * fq; \
    const float is = 7.0f / (1.0f + 10.0f * fq); \
    const float S  = 1.2011224087864498f; \
    C1_##j = is * S; C0_##j = -mu * is * S; }
    MKC(0) MKC(1) MKC(2) MKC(3) MKC(4) MKC(5) MKC(6) MKC(7)
#undef MKC

    floatx4 acc0 = {0.f, 0.f, 0.f, 0.f};
    floatx4 acc1 = {0.f, 0.f, 0.f, 0.f};
    const half8* lw8 = (const half8*)lds_w1;
    const int bo0 = (ng * 2) * 64 + lane;       // ntile = ng*2 chunk index
    const int bo1 = (ng * 2 + 1) * 64 + lane;   // ntile = ng*2+1
    const float* drow = lds_dist + (mh * 16 + m) * DLD;

    for (int tile = 0; tile < NTILES; ++tile) {
        __syncthreads();   // previous tile consumed (also fences phases 1-2)
        {   // stage 2 pairs = 512 chunks of 16 B, contiguous in ws
            const uint4* src = (const uint4*)(ws + (size_t)tile * 512);
            uint4* dst = (uint4*)lds_w1;
            dst[tid]       = src[tid];
            dst[tid + 256] = src[tid + 256];
        }
        __syncthreads();   // tile visible
#pragma unroll
        for (int pl = 0; pl < 2; ++pl) {
            const float d = drow[tile * 2 + pl];
            half8 a;
#define AJ(j) { const float t = fmaf(d, C1_##j, C0_##j); \
                a[j] = (_Float16)exp2f(-(t * t)); }
            AJ(0) AJ(1) AJ(2) AJ(3) AJ(4) AJ(5) AJ(6) AJ(7)
#undef AJ
            const half8 bf0 = lw8[pl * 256 + bo0];
            const half8 bf1 = lw8[pl * 256 + bo1];
            acc0 = __builtin_amdgcn_mfma_f32_16x16x32_f16(a, bf0, acc0, 0, 0, 0);
            acc1 = __builtin_amdgcn_mfma_f32_16x16x32_f16(a, bf1, acc1, 0, 0, 0);
        }
    }

    // ---- h1 = ssp(acc + b1) -> LDS. C/D: col = lane&15, row = quad*4+reg ----
    {
        const int colbase = ng * 32;
        const float bb0 = b1[colbase + m];
        const float bb1 = b1[colbase + 16 + m];
        const int er = mh * 16 + quad * 4;
        lds_h1[(er + 0) * H1LD + colbase + m]      = ssp(acc0[0] + bb0);
        lds_h1[(er + 1) * H1LD + colbase + m]      = ssp(acc0[1] + bb0);
        lds_h1[(er + 2) * H1LD + colbase + m]      = ssp(acc0[2] + bb0);
        lds_h1[(er + 3) * H1LD + colbase + m]      = ssp(acc0[3] + bb0);
        lds_h1[(er + 0) * H1LD + colbase + 16 + m] = ssp(acc1[0] + bb1);
        lds_h1[(er + 1) * H1LD + colbase + 16 + m] = ssp(acc1[1] + bb1);
        lds_h1[(er + 2) * H1LD + colbase + 16 + m] = ssp(acc1[2] + bb1);
        lds_h1[(er + 3) * H1LD + colbase + 16 + m] = ssp(acc1[3] + bb1);
    }
    __syncthreads();

    // ---- tail: asy + layers 2/3 (R6-verified structure) ----
    const int b_local = tid >> 3;
    const int g       = tid & 7;
    const int b       = blockIdx.x * TB + b_local;
    const float4 ch = *(const float4*)charges;

    float asy = 0.0f;
#pragma unroll
    for (int i = 0; i < 8; ++i) {
        const int p = g + 8 * i;
        const float dd = lds_dist[b_local * DLD + p];
        const int n = p & 3;
        const float Z = (n < 2) ? ((n == 0) ? ch.x : ch.y)
                                : ((n == 2) ? ch.z : ch.w);
        asy += (Z * dd + dd * dd) / (1.0f + dd);   // decay = sqrt(2*0.5) = 1
    }
    asy = redg(asy);

    const float4* __restrict__ W2v = (const float4*)W2;
    const float4* __restrict__ b2v = (const float4*)b2;
    const int wbi = g * 2;
    const float4 b2a = b2v[wbi], b2b = b2v[wbi + 1];
    float s0 = b2a.x, s1 = b2a.y, s2 = b2a.z, s3 = b2a.w;
    float s4 = b2b.x, s5 = b2b.y, s6 = b2b.z, s7 = b2b.w;

    const float* __restrict__ h1row = lds_h1 + b_local * H1LD;
    for (int k = 0; k < HIDDEN; ++k) {
        const float hk  = h1row[k];
        const float4 wa = W2v[k * 16 + wbi];
        const float4 wb = W2v[k * 16 + wbi + 1];
        s0 = fmaf(hk, wa.x, s0); s1 = fmaf(hk, wa.y, s1);
        s2 = fmaf(hk, wa.z, s2); s3 = fmaf(hk, wa.w, s3);
        s4 = fmaf(hk, wb.x, s4); s5 = fmaf(hk, wb.y, s5);
        s6 = fmaf(hk, wb.z, s6); s7 = fmaf(hk, wb.w, s7);
    }

    const float4* __restrict__ W3v = (const float4*)W3;
    const float4 w3a = W3v[wbi], w3b = W3v[wbi + 1];
    float part = ssp(s0) * w3a.x + ssp(s1) * w3a.y
               + ssp(s2) * w3a.z + ssp(s3) * w3a.w
               + ssp(s4) * w3b.x + ssp(s5) * w3b.y
               + ssp(s6) * w3b.z + ssp(s7) * w3b.w;
    part = redg(part);

    if (g == 0) {
        const float ys = part + b3[0];
        out[b] = __expf(ys) * __expf(-asy);
    }
}

extern "C" void kernel_launch(void* const* d_in, const int* in_sizes, int n_in,
                              void* d_out, int out_size, void* d_ws, size_t ws_size,
                              hipStream_t stream) {
    const float* rs      = (const float*)d_in[0];
    const float* coords  = (const float*)d_in[1];
    const float* charges = (const float*)d_in[2];
    const float* W1      = (const float*)d_in[3];
    const float* b1      = (const float*)d_in[4];
    const float* W2      = (const float*)d_in[5];
    const float* b2      = (const float*)d_in[6];
    const float* W3      = (const float*)d_in[7];
    const float* b3      = (const float*)d_in[8];
    float* out = (float*)d_out;

    const int batch = in_sizes[0] / (N_EL * 3);   // 32768
    half8* ws = (half8*)d_ws;                     // 736 KB of scratch used

    // 184*4*64 = 47104 chunks, one thread each
    prep_w1_kernel<<<184, 256, 0, stream>>>(W1, ws);

    wfnet_kernel<<<batch / TB, BLOCK, 0, stream>>>(rs, coords, charges, ws,
                                                   b1, W2, b2, W3, b3, out);
}

// Round 8
// 187.025 us; speedup vs baseline: 27.7377x; 1.2086x over previous
//
#include <hip/hip_runtime.h>
#include <math.h>

#define N_EL    16
#define N_NUC   4
#define N_FEATS 32
#define N_PAIRS 184
#define HIDDEN  64
#define TB      32           // batch elements per block
#define BLOCK   256
#define DLD     185          // dist LDS stride
#define H1LD    68           // h1 stride in reduction region
#define KWAVES  4            // K split across 4 waves
#define KP      46           // pairs per K-wave (4*46 = 184)

typedef _Float16 half8   __attribute__((ext_vector_type(8)));
typedef float    floatx16 __attribute__((ext_vector_type(16)));

// triu_indices(16, 1)
__constant__ unsigned char c_I[120] = {
    0,0,0,0,0,0,0,0,0,0,0,0,0,0,0,
    1,1,1,1,1,1,1,1,1,1,1,1,1,1,
    2,2,2,2,2,2,2,2,2,2,2,2,2,
    3,3,3,3,3,3,3,3,3,3,3,3,
    4,4,4,4,4,4,4,4,4,4,4,
    5,5,5,5,5,5,5,5,5,5,
    6,6,6,6,6,6,6,6,6,
    7,7,7,7,7,7,7,7,
    8,8,8,8,8,8,8,
    9,9,9,9,9,9,
    10,10,10,10,10,
    11,11,11,11,
    12,12,12,
    13,13,
    14
};
__constant__ unsigned char c_J[120] = {
    1,2,3,4,5,6,7,8,9,10,11,12,13,14,15,
    2,3,4,5,6,7,8,9,10,11,12,13,14,15,
    3,4,5,6,7,8,9,10,11,12,13,14,15,
    4,5,6,7,8,9,10,11,12,13,14,15,
    5,6,7,8,9,10,11,12,13,14,15,
    6,7,8,9,10,11,12,13,14,15,
    7,8,9,10,11,12,13,14,15,
    8,9,10,11,12,13,14,15,
    9,10,11,12,13,14,15,
    10,11,12,13,14,15,
    11,12,13,14,15,
    12,13,14,15,
    13,14,15,
    14,15,
    15
};

__device__ __forceinline__ float ssp(float x) {
    float a = fabsf(x);
    return fmaxf(x, 0.0f) + log1pf(__expf(-a)) - 0.69314718056f;
}
__device__ __forceinline__ float redg(float v) {
    v += __shfl_xor(v, 1);
    v += __shfl_xor(v, 2);
    v += __shfl_xor(v, 4);
    return v;
}

// ---------------------------------------------------------------------------
// Prep: scramble W1 (fp32 [5888][64]) into fp16 32x32x16 B-fragment order.
// Chunk id = p*256 + (kb*2+nh)*64 + lane; chunk holds
// B[k = kb*16 + (lane>>5)*8 + j][n = nh*32 + (lane&31)], j = 0..7.
// ---------------------------------------------------------------------------
__global__ __launch_bounds__(256)
void prep_w1_kernel(const float* __restrict__ W1, half8* __restrict__ ws)
{
    const int gid  = blockIdx.x * 256 + threadIdx.x;   // 0..47103
    const int lane = gid & 63;
    const int cidx = (gid >> 6) & 3;   // kb*2 + nh
    const int p    = gid >> 8;
    const int nh   = cidx & 1, kb = cidx >> 1;
    const float* src = W1 + (size_t)(p * 32 + kb * 16 + (lane >> 5) * 8) * 64
                          + nh * 32 + (lane & 31);
    half8 h;
    h[0] = (_Float16)src[0 * 64]; h[1] = (_Float16)src[1 * 64];
    h[2] = (_Float16)src[2 * 64]; h[3] = (_Float16)src[3 * 64];
    h[4] = (_Float16)src[4 * 64]; h[5] = (_Float16)src[5 * 64];
    h[6] = (_Float16)src[6 * 64]; h[7] = (_Float16)src[7 * 64];
    ws[gid] = h;
}

// ---------------------------------------------------------------------------
// Main: block = 32 elements, 4 waves. Wave kh owns ALL 32 elements x ALL 64
// columns over K-range pairs [kh*46, kh*46+46) -> zero A-frag redundancy and
// ZERO barriers in the K loop (B-frags stream global->VGPR directly).
// kh-partials reduced through LDS at the end.
// ---------------------------------------------------------------------------
__global__ __launch_bounds__(BLOCK)
void wfnet_kernel(const float* __restrict__ rs,
                  const float* __restrict__ coords,
                  const float* __restrict__ charges,
                  const half8* __restrict__ ws,
                  const float* __restrict__ b1,
                  const float* __restrict__ W2,
                  const float* __restrict__ b2,
                  const float* __restrict__ W3,
                  const float* __restrict__ b3,
                  float* __restrict__ out)
{
    __shared__ float lds_red[4096];        // 16 KB: rs stage / kh-reduce / h1
    __shared__ float lds_dist[TB * DLD];   // 23.1 KB

    const int tid  = threadIdx.x;
    const int wave = tid >> 6;             // = kh
    const int lane = tid & 63;
    const int m    = lane & 31;            // element row
    const int lh   = lane >> 5;            // k-half within fragment

    // ---- phase 1: stage rs (transient, in lds_red) ----
    {
        float* lds_rs = lds_red;
        const float* rs_blk = rs + (size_t)blockIdx.x * (TB * N_EL * 3);
        for (int k = tid; k < TB * N_EL * 3; k += BLOCK) lds_rs[k] = rs_blk[k];
    }
    __syncthreads();

    // ---- phase 2: all 184 distances per element -> lds_dist ----
    {
        const int bl = tid >> 3, g = tid & 7;
        const float* myrs = lds_red + bl * (N_EL * 3);
        float* dst = lds_dist + bl * DLD;
        for (int i = 0; i < 8; ++i) {
            const int p = g + 8 * i;
            const int e = p >> 2, n = p & 3;
            const float dx = myrs[e * 3 + 0] - coords[n * 3 + 0];
            const float dy = myrs[e * 3 + 1] - coords[n * 3 + 1];
            const float dz = myrs[e * 3 + 2] - coords[n * 3 + 2];
            dst[p] = sqrtf(dx * dx + dy * dy + dz * dz);
        }
        for (int i = 0; i < 15; ++i) {
            const int q  = g + 8 * i;
            const int ei = 3 * (int)c_I[q], ej = 3 * (int)c_J[q];
            const float dx = myrs[ei + 0] - myrs[ej + 0];
            const float dy = myrs[ei + 1] - myrs[ej + 1];
            const float dz = myrs[ei + 2] - myrs[ej + 2];
            dst[64 + q] = sqrtf(dx * dx + dy * dy + dz * dz);
        }
    }
    __syncthreads();

    // per-lane Gaussian constants: kb0 features f0+j, kb1 features 16+f0+j
    // x = exp(-((d-mu)/sg)^2) = 2^(-(d*P1 + P0)^2), S = sqrt(log2 e)
    const int f0 = lh * 8;
#define MKC(P, FF) float P##1, P##0; { \
    const float fq = (float)(FF) * (1.0f / 31.0f); \
    const float mu = 10.0f * fq * fq; \
    const float is = 7.0f / (1.0f + 10.0f * fq); \
    P##1 = is * 1.2011224087864498f; \
    P##0 = -mu * P##1; }
    MKC(C0_, f0 + 0) MKC(C1_, f0 + 1) MKC(C2_, f0 + 2) MKC(C3_, f0 + 3)
    MKC(C4_, f0 + 4) MKC(C5_, f0 + 5) MKC(C6_, f0 + 6) MKC(C7_, f0 + 7)
    MKC(D0_, f0 + 16) MKC(D1_, f0 + 17) MKC(D2_, f0 + 18) MKC(D3_, f0 + 19)
    MKC(D4_, f0 + 20) MKC(D5_, f0 + 21) MKC(D6_, f0 + 22) MKC(D7_, f0 + 23)
#undef MKC

    // ---- K loop: 46 pairs, no barriers. B-frags prefetched depth-1. ----
    floatx16 accA = {};   // cols 0..31
    floatx16 accB = {};   // cols 32..63
    const half8* wp = ws + ((size_t)(wave * KP) * 256 + lane);
    half8 p0 = wp[0], p1 = wp[64], p2 = wp[128], p3 = wp[192];
    const float* drow = lds_dist + m * DLD + wave * KP;

    for (int r = 0; r < KP; ++r) {
        const float d = drow[r];
        half8 a0, a1;
#define AJ0(j) { const float t = fmaf(d, C##j##_1, C##j##_0); \
                 a0[j] = (_Float16)exp2f(-(t * t)); }
#define AJ1(j) { const float t = fmaf(d, D##j##_1, D##j##_0); \
                 a1[j] = (_Float16)exp2f(-(t * t)); }
        AJ0(0) AJ0(1) AJ0(2) AJ0(3) AJ0(4) AJ0(5) AJ0(6) AJ0(7)
        AJ1(0) AJ1(1) AJ1(2) AJ1(3) AJ1(4) AJ1(5) AJ1(6) AJ1(7)
#undef AJ0
#undef AJ1
        const half8 b00 = p0, b01 = p1, b10 = p2, b11 = p3;
        if (r + 1 < KP) {
            wp += 256;
            p0 = wp[0]; p1 = wp[64]; p2 = wp[128]; p3 = wp[192];
        }
        accA = __builtin_amdgcn_mfma_f32_32x32x16_f16(a0, b00, accA, 0, 0, 0);
        accB = __builtin_amdgcn_mfma_f32_32x32x16_f16(a0, b01, accB, 0, 0, 0);
        accA = __builtin_amdgcn_mfma_f32_32x32x16_f16(a1, b10, accA, 0, 0, 0);
        accB = __builtin_amdgcn_mfma_f32_32x32x16_f16(a1, b11, accB, 0, 0, 0);
    }

    // ---- kh reduction through lds_red.
    // C/D: col = lane&31 (+nh*32), row el = (rg&3) + 8*(rg>>2) + 4*lh ----
    if (wave >= 2) {
        float* dst = lds_red + (wave - 2) * 2048;
#pragma unroll
        for (int rg = 0; rg < 16; ++rg) {
            const int el = (rg & 3) + 8 * (rg >> 2) + 4 * lh;
            dst[el * 64 + m]      = accA[rg];
            dst[el * 64 + 32 + m] = accB[rg];
        }
    }
    __syncthreads();
    if (wave < 2) {
        const float* srcr = lds_red + wave * 2048;
#pragma unroll
        for (int rg = 0; rg < 16; ++rg) {
            const int el = (rg & 3) + 8 * (rg >> 2) + 4 * lh;
            accA[rg] += srcr[el * 64 + m];
            accB[rg] += srcr[el * 64 + 32 + m];
        }
    }
    __syncthreads();
    if (wave == 1) {
#pragma unroll
        for (int rg = 0; rg < 16; ++rg) {
            const int el = (rg & 3) + 8 * (rg >> 2) + 4 * lh;
            lds_red[el * 64 + m]      = accA[rg];
            lds_red[el * 64 + 32 + m] = accB[rg];
        }
    }
    __syncthreads();
    if (wave == 0) {
        const float bA = b1[m], bB = b1[32 + m];
#pragma unroll
        for (int rg = 0; rg < 16; ++rg) {
            const int el = (rg & 3) + 8 * (rg >> 2) + 4 * lh;
            accA[rg] += lds_red[el * 64 + m];
            accB[rg] += lds_red[el * 64 + 32 + m];
        }
        // all reads above retire before these writes (same wave, in-order LDS)
#pragma unroll
        for (int rg = 0; rg < 16; ++rg) {
            const int el = (rg & 3) + 8 * (rg >> 2) + 4 * lh;
            lds_red[el * H1LD + m]      = ssp(accA[rg] + bA);
            lds_red[el * H1LD + 32 + m] = ssp(accB[rg] + bB);
        }
    }
    __syncthreads();

    // ---- tail: asy + layers 2/3 (R6/R7-verified structure) ----
    const int b_local = tid >> 3;
    const int g       = tid & 7;
    const int b       = blockIdx.x * TB + b_local;
    const float4 ch = *(const float4*)charges;

    float asy = 0.0f;
#pragma unroll
    for (int i = 0; i < 8; ++i) {
        const int p = g + 8 * i;
        const float dd = lds_dist[b_local * DLD + p];
        const int n = p & 3;
        const float Z = (n < 2) ? ((n == 0) ? ch.x : ch.y)
                                : ((n == 2) ? ch.z : ch.w);
        asy += (Z * dd + dd * dd) / (1.0f + dd);   // decay = sqrt(2*0.5) = 1
    }
    asy = redg(asy);

    const float4* __restrict__ W2v = (const float4*)W2;
    const float4* __restrict__ b2v = (const float4*)b2;
    const int wbi = g * 2;
    const float4 b2a = b2v[wbi], b2b = b2v[wbi + 1];
    float s0 = b2a.x, s1 = b2a.y, s2 = b2a.z, s3 = b2a.w;
    float s4 = b2b.x, s5 = b2b.y, s6 = b2b.z, s7 = b2b.w;

    const float* __restrict__ h1row = lds_red + b_local * H1LD;
    for (int k = 0; k < HIDDEN; ++k) {
        const float hk  = h1row[k];
        const float4 wa = W2v[k * 16 + wbi];
        const float4 wb = W2v[k * 16 + wbi + 1];
        s0 = fmaf(hk, wa.x, s0); s1 = fmaf(hk, wa.y, s1);
        s2 = fmaf(hk, wa.z, s2); s3 = fmaf(hk, wa.w, s3);
        s4 = fmaf(hk, wb.x, s4); s5 = fmaf(hk, wb.y, s5);
        s6 = fmaf(hk, wb.z, s6); s7 = fmaf(hk, wb.w, s7);
    }

    const float4* __restrict__ W3v = (const float4*)W3;
    const float4 w3a = W3v[wbi], w3b = W3v[wbi + 1];
    float part = ssp(s0) * w3a.x + ssp(s1) * w3a.y
               + ssp(s2) * w3a.z + ssp(s3) * w3a.w
               + ssp(s4) * w3b.x + ssp(s5) * w3b.y
               + ssp(s6) * w3b.z + ssp(s7) * w3b.w;
    part = redg(part);

    if (g == 0) {
        const float ys = part + b3[0];
        out[b] = __expf(ys) * __expf(-asy);
    }
}

extern "C" void kernel_launch(void* const* d_in, const int* in_sizes, int n_in,
                              void* d_out, int out_size, void* d_ws, size_t ws_size,
                              hipStream_t stream) {
    const float* rs      = (const float*)d_in[0];
    const float* coords  = (const float*)d_in[1];
    const float* charges = (const float*)d_in[2];
    const float* W1      = (const float*)d_in[3];
    const float* b1      = (const float*)d_in[4];
    const float* W2      = (const float*)d_in[5];
    const float* b2      = (const float*)d_in[6];
    const float* W3      = (const float*)d_in[7];
    const float* b3      = (const float*)d_in[8];
    float* out = (float*)d_out;

    const int batch = in_sizes[0] / (N_EL * 3);   // 32768
    half8* ws = (half8*)d_ws;                     // 736 KB scratch

    prep_w1_kernel<<<184, 256, 0, stream>>>(W1, ws);
    wfnet_kernel<<<batch / TB, BLOCK, 0, stream>>>(rs, coords, charges, ws,
                                                   b1, W2, b2, W3, b3, out);
}

// Round 10
// 160.852 us; speedup vs baseline: 32.2509x; 1.1627x over previous
//
#include <hip/hip_runtime.h>
#include <math.h>

#define N_EL    16
#define N_NUC   4
#define N_FEATS 32
#define N_PAIRS 184
#define HIDDEN  64
#define TB      32           // batch elements per block
#define BLOCK   256
#define DLD     185          // dist LDS stride
#define H1LD    68           // h1 stride (inside reused dist region)
#define KP      46           // pairs per K-wave (4*46 = 184)

typedef _Float16 half8  __attribute__((ext_vector_type(8)));
typedef __fp16   fp16x2 __attribute__((ext_vector_type(2)));  // cvt_pkrtz ret type
typedef float    floatx16 __attribute__((ext_vector_type(16)));

#if __has_builtin(__builtin_amdgcn_exp2f)
#define EXP2(x) __builtin_amdgcn_exp2f(x)   // bare v_exp_f32 (no ocml wrapper)
#else
#define EXP2(x) exp2f(x)
#endif

// triu_indices(16, 1)
__constant__ unsigned char c_I[120] = {
    0,0,0,0,0,0,0,0,0,0,0,0,0,0,0,
    1,1,1,1,1,1,1,1,1,1,1,1,1,1,
    2,2,2,2,2,2,2,2,2,2,2,2,2,
    3,3,3,3,3,3,3,3,3,3,3,3,
    4,4,4,4,4,4,4,4,4,4,4,
    5,5,5,5,5,5,5,5,5,5,
    6,6,6,6,6,6,6,6,6,
    7,7,7,7,7,7,7,7,
    8,8,8,8,8,8,8,
    9,9,9,9,9,9,
    10,10,10,10,10,
    11,11,11,11,
    12,12,12,
    13,13,
    14
};
__constant__ unsigned char c_J[120] = {
    1,2,3,4,5,6,7,8,9,10,11,12,13,14,15,
    2,3,4,5,6,7,8,9,10,11,12,13,14,15,
    3,4,5,6,7,8,9,10,11,12,13,14,15,
    4,5,6,7,8,9,10,11,12,13,14,15,
    5,6,7,8,9,10,11,12,13,14,15,
    6,7,8,9,10,11,12,13,14,15,
    7,8,9,10,11,12,13,14,15,
    8,9,10,11,12,13,14,15,
    9,10,11,12,13,14,15,
    10,11,12,13,14,15,
    11,12,13,14,15,
    12,13,14,15,
    13,14,15,
    14,15,
    15
};

__device__ __forceinline__ float ssp(float x) {
    float a = fabsf(x);
    return fmaxf(x, 0.0f) + log1pf(__expf(-a)) - 0.69314718056f;
}
__device__ __forceinline__ float redg(float v) {
    v += __shfl_xor(v, 1);
    v += __shfl_xor(v, 2);
    v += __shfl_xor(v, 4);
    return v;
}

// ---------------------------------------------------------------------------
// Prep: one block per pair. Coalesced 8 KB load of W1[pair] into LDS, then
// each thread assembles one 16 B B-fragment chunk (conflict-free reads).
// Chunk id = p*256 + (kb*2+nh)*64 + lane; holds
// B[k = kb*16 + (lane>>5)*8 + j][n = nh*32 + (lane&31)], j = 0..7.
// ---------------------------------------------------------------------------
__global__ __launch_bounds__(256)
void prep_w1_kernel(const float* __restrict__ W1, half8* __restrict__ ws)
{
    __shared__ float w[N_FEATS * HIDDEN];   // 8 KB: one pair's rows
    const int p = blockIdx.x;
    const float* src = W1 + (size_t)p * (N_FEATS * HIDDEN);
    for (int k = threadIdx.x; k < N_FEATS * HIDDEN; k += 256) w[k] = src[k];
    __syncthreads();

    const int tid  = threadIdx.x;
    const int lane = tid & 63;
    const int cidx = tid >> 6;              // kb*2 + nh
    const int nh = cidx & 1, kb = cidx >> 1;
    const int krow = kb * 16 + (lane >> 5) * 8;
    const int n    = nh * 32 + (lane & 31);
    half8 h;
#pragma unroll
    for (int j = 0; j < 8; ++j) h[j] = (_Float16)w[(krow + j) * 64 + n];
    ws[(size_t)p * 256 + tid] = h;
}

// ---------------------------------------------------------------------------
// Main: block = 32 elements, 4 waves; wave kh owns all 32 el x 64 cols over
// pairs [kh*46, kh*46+46). No barriers in the K loop. After the K loop the
// dist region is reused for the kh-reduction and h1 (saves 16 KB -> 4
// blocks/CU resident, kills the R8 serialization tail).
// ---------------------------------------------------------------------------
__global__ __launch_bounds__(BLOCK)
void wfnet_kernel(const float* __restrict__ rs,
                  const float* __restrict__ coords,
                  const float* __restrict__ charges,
                  const half8* __restrict__ ws,
                  const float* __restrict__ b1,
                  const float* __restrict__ W2,
                  const float* __restrict__ b2,
                  const float* __restrict__ W3,
                  const float* __restrict__ b3,
                  float* __restrict__ out)
{
    __shared__ float lds_rs[TB * N_EL * 3];   // 6 KB
    __shared__ float lds_dist[TB * DLD];      // 23.7 KB; reused as red/h1 later

    const int tid  = threadIdx.x;
    const int wave = tid >> 6;               // = kh
    const int lane = tid & 63;
    const int m    = lane & 31;              // element row
    const int lh   = lane >> 5;              // k-half within fragment

    // ---- phase 1: stage rs ----
    {
        const float* rs_blk = rs + (size_t)blockIdx.x * (TB * N_EL * 3);
        for (int k = tid; k < TB * N_EL * 3; k += BLOCK) lds_rs[k] = rs_blk[k];
    }
    __syncthreads();

    // ---- phase 2: distances -> lds_dist; asy partial stays in a register
    // (thread (bl,g) mapping here == tail mapping, so no LDS needed) ----
    float asy = 0.0f;
    {
        const int bl = tid >> 3, g = tid & 7;
        const float* myrs = lds_rs + bl * (N_EL * 3);
        float* dst = lds_dist + bl * DLD;
        const float4 ch = *(const float4*)charges;
        for (int i = 0; i < 8; ++i) {
            const int p = g + 8 * i;
            const int e = p >> 2, n = p & 3;
            const float dx = myrs[e * 3 + 0] - coords[n * 3 + 0];
            const float dy = myrs[e * 3 + 1] - coords[n * 3 + 1];
            const float dz = myrs[e * 3 + 2] - coords[n * 3 + 2];
            const float d = sqrtf(dx * dx + dy * dy + dz * dz);
            dst[p] = d;
            const float Z = (n < 2) ? ((n == 0) ? ch.x : ch.y)
                                    : ((n == 2) ? ch.z : ch.w);
            asy += (Z * d + d * d) / (1.0f + d);   // decay = sqrt(2*0.5) = 1
        }
        for (int i = 0; i < 15; ++i) {
            const int q  = g + 8 * i;
            const int ei = 3 * (int)c_I[q], ej = 3 * (int)c_J[q];
            const float dx = myrs[ei + 0] - myrs[ej + 0];
            const float dy = myrs[ei + 1] - myrs[ej + 1];
            const float dz = myrs[ei + 2] - myrs[ej + 2];
            dst[64 + q] = sqrtf(dx * dx + dy * dy + dz * dz);
        }
    }
    __syncthreads();

    // per-lane Gaussian constants: x = 2^(-(d*P1+P0)^2), S = sqrt(log2 e)
    const int f0 = lh * 8;
#define MKC(P, FF) float P##1, P##0; { \
    const float fq = (float)(FF) * (1.0f / 31.0f); \
    const float mu = 10.0f * fq * fq; \
    const float is = 7.0f / (1.0f + 10.0f * fq); \
    P##1 = is * 1.2011224087864498f; \
    P##0 = -mu * P##1; }
    MKC(C0_, f0 + 0) MKC(C1_, f0 + 1) MKC(C2_, f0 + 2) MKC(C3_, f0 + 3)
    MKC(C4_, f0 + 4) MKC(C5_, f0 + 5) MKC(C6_, f0 + 6) MKC(C7_, f0 + 7)
    MKC(D0_, f0 + 16) MKC(D1_, f0 + 17) MKC(D2_, f0 + 18) MKC(D3_, f0 + 19)
    MKC(D4_, f0 + 20) MKC(D5_, f0 + 21) MKC(D6_, f0 + 22) MKC(D7_, f0 + 23)
#undef MKC

    // ---- K loop: 46 pairs, no barriers, B prefetch depth-1 ----
    floatx16 accA = {};   // cols 0..31
    floatx16 accB = {};   // cols 32..63
    const half8* wp = ws + ((size_t)(wave * KP) * 256 + lane);
    half8 p0 = wp[0], p1 = wp[64], p2 = wp[128], p3 = wp[192];
    const float* drow = lds_dist + m * DLD + wave * KP;

    for (int r = 0; r < KP; ++r) {
        const float d = drow[r];
#define XT(P) ({ const float t_ = fmaf(d, P##1, P##0); EXP2(-(t_ * t_)); })
        union { half8 v; fp16x2 h[4]; } ua, ub;
        ua.h[0] = __builtin_amdgcn_cvt_pkrtz(XT(C0_), XT(C1_));
        ua.h[1] = __builtin_amdgcn_cvt_pkrtz(XT(C2_), XT(C3_));
        ua.h[2] = __builtin_amdgcn_cvt_pkrtz(XT(C4_), XT(C5_));
        ua.h[3] = __builtin_amdgcn_cvt_pkrtz(XT(C6_), XT(C7_));
        ub.h[0] = __builtin_amdgcn_cvt_pkrtz(XT(D0_), XT(D1_));
        ub.h[1] = __builtin_amdgcn_cvt_pkrtz(XT(D2_), XT(D3_));
        ub.h[2] = __builtin_amdgcn_cvt_pkrtz(XT(D4_), XT(D5_));
        ub.h[3] = __builtin_amdgcn_cvt_pkrtz(XT(D6_), XT(D7_));
#undef XT
        const half8 b00 = p0, b01 = p1, b10 = p2, b11 = p3;
        if (r + 1 < KP) {
            wp += 256;
            p0 = wp[0]; p1 = wp[64]; p2 = wp[128]; p3 = wp[192];
        }
        accA = __builtin_amdgcn_mfma_f32_32x32x16_f16(ua.v, b00, accA, 0, 0, 0);
        accB = __builtin_amdgcn_mfma_f32_32x32x16_f16(ua.v, b01, accB, 0, 0, 0);
        accA = __builtin_amdgcn_mfma_f32_32x32x16_f16(ub.v, b10, accA, 0, 0, 0);
        accB = __builtin_amdgcn_mfma_f32_32x32x16_f16(ub.v, b11, accB, 0, 0, 0);
    }

    __syncthreads();   // all K-loops done -> dist region reused as red/h1
    float* lds_red = lds_dist;   // 16 KB red region + h1 live inside it

    // ---- kh reduction. C/D: col = lane&31 (+nh*32),
    //      row el = (rg&3) + 8*(rg>>2) + 4*lh ----
    if (wave >= 2) {
        float* dst = lds_red + (wave - 2) * 2048;
#pragma unroll
        for (int rg = 0; rg < 16; ++rg) {
            const int el = (rg & 3) + 8 * (rg >> 2) + 4 * lh;
            dst[el * 64 + m]      = accA[rg];
            dst[el * 64 + 32 + m] = accB[rg];
        }
    }
    __syncthreads();
    if (wave < 2) {
        const float* srcr = lds_red + wave * 2048;
#pragma unroll
        for (int rg = 0; rg < 16; ++rg) {
            const int el = (rg & 3) + 8 * (rg >> 2) + 4 * lh;
            accA[rg] += srcr[el * 64 + m];
            accB[rg] += srcr[el * 64 + 32 + m];
        }
    }
    __syncthreads();
    if (wave == 1) {
#pragma unroll
        for (int rg = 0; rg < 16; ++rg) {
            const int el = (rg & 3) + 8 * (rg >> 2) + 4 * lh;
            lds_red[el * 64 + m]      = accA[rg];
            lds_red[el * 64 + 32 + m] = accB[rg];
        }
    }
    __syncthreads();
    if (wave == 0) {
        const float bA = b1[m], bB = b1[32 + m];
#pragma unroll
        for (int rg = 0; rg < 16; ++rg) {
            const int el = (rg & 3) + 8 * (rg >> 2) + 4 * lh;
            accA[rg] += lds_red[el * 64 + m];
            accB[rg] += lds_red[el * 64 + 32 + m];
        }
        // wave-0 LDS ops are in-order: reads above retire before these writes
#pragma unroll
        for (int rg = 0; rg < 16; ++rg) {
            const int el = (rg & 3) + 8 * (rg >> 2) + 4 * lh;
            lds_red[el * H1LD + m]      = ssp(accA[rg] + bA);
            lds_red[el * H1LD + 32 + m] = ssp(accB[rg] + bB);
        }
    }
    __syncthreads();

    // ---- tail: layers 2/3 (asy already in a register) ----
    const int b_local = tid >> 3;
    const int g       = tid & 7;
    const int b       = blockIdx.x * TB + b_local;
    asy = redg(asy);

    const float4* __restrict__ W2v = (const float4*)W2;
    const float4* __restrict__ b2v = (const float4*)b2;
    const int wbi = g * 2;
    const float4 b2a = b2v[wbi], b2b = b2v[wbi + 1];
    float s0 = b2a.x, s1 = b2a.y, s2 = b2a.z, s3 = b2a.w;
    float s4 = b2b.x, s5 = b2b.y, s6 = b2b.z, s7 = b2b.w;

    const float* __restrict__ h1row = lds_red + b_local * H1LD;
    for (int k = 0; k < HIDDEN; ++k) {
        const float hk  = h1row[k];
        const float4 wa = W2v[k * 16 + wbi];
        const float4 wb = W2v[k * 16 + wbi + 1];
        s0 = fmaf(hk, wa.x, s0); s1 = fmaf(hk, wa.y, s1);
        s2 = fmaf(hk, wa.z, s2); s3 = fmaf(hk, wa.w, s3);
        s4 = fmaf(hk, wb.x, s4); s5 = fmaf(hk, wb.y, s5);
        s6 = fmaf(hk, wb.z, s6); s7 = fmaf(hk, wb.w, s7);
    }

    const float4* __restrict__ W3v = (const float4*)W3;
    const float4 w3a = W3v[wbi], w3b = W3v[wbi + 1];
    float part = ssp(s0) * w3a.x + ssp(s1) * w3a.y
               + ssp(s2) * w3a.z + ssp(s3) * w3a.w
               + ssp(s4) * w3b.x + ssp(s5) * w3b.y
               + ssp(s6) * w3b.z + ssp(s7) * w3b.w;
    part = redg(part);

    if (g == 0) {
        const float ys = part + b3[0];
        out[b] = __expf(ys) * __expf(-asy);
    }
}

extern "C" void kernel_launch(void* const* d_in, const int* in_sizes, int n_in,
                              void* d_out, int out_size, void* d_ws, size_t ws_size,
                              hipStream_t stream) {
    const float* rs      = (const float*)d_in[0];
    const float* coords  = (const float*)d_in[1];
    const float* charges = (const float*)d_in[2];
    const float* W1      = (const float*)d_in[3];
    const float* b1      = (const float*)d_in[4];
    const float* W2      = (const float*)d_in[5];
    const float* b2      = (const float*)d_in[6];
    const float* W3      = (const float*)d_in[7];
    const float* b3      = (const float*)d_in[8];
    float* out = (float*)d_out;

    const int batch = in_sizes[0] / (N_EL * 3);   // 32768
    half8* ws = (half8*)d_ws;                     // 736 KB scratch

    prep_w1_kernel<<<N_PAIRS, 256, 0, stream>>>(W1, ws);
    wfnet_kernel<<<batch / TB, BLOCK, 0, stream>>>(rs, coords, charges, ws,
                                                   b1, W2, b2, W3, b3, out);
}

// Round 11
// 159.645 us; speedup vs baseline: 32.4948x; 1.0076x over previous
//
#include <hip/hip_runtime.h>
#include <math.h>

#define N_EL    16
#define N_NUC   4
#define N_FEATS 32
#define N_PAIRS 184
#define HIDDEN  64
#define TB      32           // batch elements per block
#define BLOCK   256
#define DLD     185          // dist LDS stride
#define H1LD    68           // h1 stride (inside reused dist region)
#define KP      46           // pairs per K-wave (4*46 = 184)

typedef _Float16 half8  __attribute__((ext_vector_type(8)));
typedef __fp16   fp16x2 __attribute__((ext_vector_type(2)));  // cvt_pkrtz ret type
typedef float    floatx16 __attribute__((ext_vector_type(16)));

#if __has_builtin(__builtin_amdgcn_exp2f)
#define EXP2(x) __builtin_amdgcn_exp2f(x)   // bare v_exp_f32 (no ocml wrapper)
#else
#define EXP2(x) exp2f(x)
#endif

// triu_indices(16, 1)
__constant__ unsigned char c_I[120] = {
    0,0,0,0,0,0,0,0,0,0,0,0,0,0,0,
    1,1,1,1,1,1,1,1,1,1,1,1,1,1,
    2,2,2,2,2,2,2,2,2,2,2,2,2,
    3,3,3,3,3,3,3,3,3,3,3,3,
    4,4,4,4,4,4,4,4,4,4,4,
    5,5,5,5,5,5,5,5,5,5,
    6,6,6,6,6,6,6,6,6,
    7,7,7,7,7,7,7,7,
    8,8,8,8,8,8,8,
    9,9,9,9,9,9,
    10,10,10,10,10,
    11,11,11,11,
    12,12,12,
    13,13,
    14
};
__constant__ unsigned char c_J[120] = {
    1,2,3,4,5,6,7,8,9,10,11,12,13,14,15,
    2,3,4,5,6,7,8,9,10,11,12,13,14,15,
    3,4,5,6,7,8,9,10,11,12,13,14,15,
    4,5,6,7,8,9,10,11,12,13,14,15,
    5,6,7,8,9,10,11,12,13,14,15,
    6,7,8,9,10,11,12,13,14,15,
    7,8,9,10,11,12,13,14,15,
    8,9,10,11,12,13,14,15,
    9,10,11,12,13,14,15,
    10,11,12,13,14,15,
    11,12,13,14,15,
    12,13,14,15,
    13,14,15,
    14,15,
    15
};

__device__ __forceinline__ float ssp(float x) {
    float a = fabsf(x);
    return fmaxf(x, 0.0f) + log1pf(__expf(-a)) - 0.69314718056f;
}
__device__ __forceinline__ float redg(float v) {
    v += __shfl_xor(v, 1);
    v += __shfl_xor(v, 2);
    v += __shfl_xor(v, 4);
    return v;
}

// ---------------------------------------------------------------------------
// Prep: one block per pair. Coalesced 8 KB load of W1[pair] into LDS, then
// each thread assembles one 16 B B-fragment chunk (conflict-free reads).
// Chunk id = p*256 + (kb*2+nh)*64 + lane; holds
// B[k = kb*16 + (lane>>5)*8 + j][n = nh*32 + (lane&31)], j = 0..7.
// ---------------------------------------------------------------------------
__global__ __launch_bounds__(256)
void prep_w1_kernel(const float* __restrict__ W1, half8* __restrict__ ws)
{
    __shared__ float w[N_FEATS * HIDDEN];   // 8 KB: one pair's rows
    const int p = blockIdx.x;
    const float* src = W1 + (size_t)p * (N_FEATS * HIDDEN);
    for (int k = threadIdx.x; k < N_FEATS * HIDDEN; k += 256) w[k] = src[k];
    __syncthreads();

    const int tid  = threadIdx.x;
    const int lane = tid & 63;
    const int cidx = tid >> 6;              // kb*2 + nh
    const int nh = cidx & 1, kb = cidx >> 1;
    const int krow = kb * 16 + (lane >> 5) * 8;
    const int n    = nh * 32 + (lane & 31);
    half8 h;
#pragma unroll
    for (int j = 0; j < 8; ++j) h[j] = (_Float16)w[(krow + j) * 64 + n];
    ws[(size_t)p * 256 + tid] = h;
}

// ---------------------------------------------------------------------------
// Main: block = 32 elements, 4 waves; wave kh owns all 32 el x 64 cols over
// pairs [kh*46, kh*46+46). K-loop unrolled x2 with TWO named fragment sets
// (pA even rounds / pB odd rounds): R10 post-mortem showed the rolling
// single-buffer prefetch cost 32 v_mov per round (36% of VALU issue).
// Distances prefetched a full double-round ahead. No barriers in K loop.
// ---------------------------------------------------------------------------
__global__ __launch_bounds__(BLOCK)
void wfnet_kernel(const float* __restrict__ rs,
                  const float* __restrict__ coords,
                  const float* __restrict__ charges,
                  const half8* __restrict__ ws,
                  const float* __restrict__ b1,
                  const float* __restrict__ W2,
                  const float* __restrict__ b2,
                  const float* __restrict__ W3,
                  const float* __restrict__ b3,
                  float* __restrict__ out)
{
    __shared__ float lds_rs[TB * N_EL * 3];   // 6 KB
    __shared__ float lds_dist[TB * DLD];      // 23.7 KB; reused as red/h1 later

    const int tid  = threadIdx.x;
    const int wave = tid >> 6;               // = kh
    const int lane = tid & 63;
    const int m    = lane & 31;              // element row
    const int lh   = lane >> 5;              // k-half within fragment

    // ---- phase 1: stage rs ----
    {
        const float* rs_blk = rs + (size_t)blockIdx.x * (TB * N_EL * 3);
        for (int k = tid; k < TB * N_EL * 3; k += BLOCK) lds_rs[k] = rs_blk[k];
    }
    __syncthreads();

    // ---- phase 2: distances -> lds_dist; asy partial stays in a register ----
    float asy = 0.0f;
    {
        const int bl = tid >> 3, g = tid & 7;
        const float* myrs = lds_rs + bl * (N_EL * 3);
        float* dst = lds_dist + bl * DLD;
        const float4 ch = *(const float4*)charges;
        for (int i = 0; i < 8; ++i) {
            const int p = g + 8 * i;
            const int e = p >> 2, n = p & 3;
            const float dx = myrs[e * 3 + 0] - coords[n * 3 + 0];
            const float dy = myrs[e * 3 + 1] - coords[n * 3 + 1];
            const float dz = myrs[e * 3 + 2] - coords[n * 3 + 2];
            const float d = sqrtf(dx * dx + dy * dy + dz * dz);
            dst[p] = d;
            const float Z = (n < 2) ? ((n == 0) ? ch.x : ch.y)
                                    : ((n == 2) ? ch.z : ch.w);
            asy += (Z * d + d * d) / (1.0f + d);   // decay = sqrt(2*0.5) = 1
        }
        for (int i = 0; i < 15; ++i) {
            const int q  = g + 8 * i;
            const int ei = 3 * (int)c_I[q], ej = 3 * (int)c_J[q];
            const float dx = myrs[ei + 0] - myrs[ej + 0];
            const float dy = myrs[ei + 1] - myrs[ej + 1];
            const float dz = myrs[ei + 2] - myrs[ej + 2];
            dst[64 + q] = sqrtf(dx * dx + dy * dy + dz * dz);
        }
    }
    __syncthreads();

    // per-lane Gaussian constants: x = 2^(-(d*P1+P0)^2), S = sqrt(log2 e)
    const int f0 = lh * 8;
#define MKC(P, FF) float P##1, P##0; { \
    const float fq = (float)(FF) * (1.0f / 31.0f); \
    const float mu = 10.0f * fq * fq; \
    const float is = 7.0f / (1.0f + 10.0f * fq); \
    P##1 = is * 1.2011224087864498f; \
    P##0 = -mu * P##1; }
    MKC(C0_, f0 + 0) MKC(C1_, f0 + 1) MKC(C2_, f0 + 2) MKC(C3_, f0 + 3)
    MKC(C4_, f0 + 4) MKC(C5_, f0 + 5) MKC(C6_, f0 + 6) MKC(C7_, f0 + 7)
    MKC(D0_, f0 + 16) MKC(D1_, f0 + 17) MKC(D2_, f0 + 18) MKC(D3_, f0 + 19)
    MKC(D4_, f0 + 20) MKC(D5_, f0 + 21) MKC(D6_, f0 + 22) MKC(D7_, f0 + 23)
#undef MKC

    // ---- K loop: 46 pairs, unroll x2, dual fragment sets, no barriers ----
    floatx16 accA = {};   // cols 0..31
    floatx16 accB = {};   // cols 32..63
    const half8* wq = ws + ((size_t)(wave * KP) * 256 + lane);
    const float* drow = lds_dist + m * DLD + wave * KP;

#define XT(P) ({ const float t_ = fmaf(d, P##1, P##0); EXP2(-(t_ * t_)); })
#define KROUND(dd, Q0, Q1, Q2, Q3) { \
    const float d = (dd); \
    union { half8 v; fp16x2 h[4]; } ua, ub; \
    ua.h[0] = __builtin_amdgcn_cvt_pkrtz(XT(C0_), XT(C1_)); \
    ua.h[1] = __builtin_amdgcn_cvt_pkrtz(XT(C2_), XT(C3_)); \
    ua.h[2] = __builtin_amdgcn_cvt_pkrtz(XT(C4_), XT(C5_)); \
    ua.h[3] = __builtin_amdgcn_cvt_pkrtz(XT(C6_), XT(C7_)); \
    ub.h[0] = __builtin_amdgcn_cvt_pkrtz(XT(D0_), XT(D1_)); \
    ub.h[1] = __builtin_amdgcn_cvt_pkrtz(XT(D2_), XT(D3_)); \
    ub.h[2] = __builtin_amdgcn_cvt_pkrtz(XT(D4_), XT(D5_)); \
    ub.h[3] = __builtin_amdgcn_cvt_pkrtz(XT(D6_), XT(D7_)); \
    accA = __builtin_amdgcn_mfma_f32_32x32x16_f16(ua.v, Q0, accA, 0, 0, 0); \
    accB = __builtin_amdgcn_mfma_f32_32x32x16_f16(ua.v, Q1, accB, 0, 0, 0); \
    accA = __builtin_amdgcn_mfma_f32_32x32x16_f16(ub.v, Q2, accA, 0, 0, 0); \
    accB = __builtin_amdgcn_mfma_f32_32x32x16_f16(ub.v, Q3, accB, 0, 0, 0); \
}

    half8 pA0 = wq[0],   pA1 = wq[64],  pA2 = wq[128], pA3 = wq[192];
    half8 pB0 = wq[256], pB1 = wq[320], pB2 = wq[384], pB3 = wq[448];
    float d0 = drow[0], d1 = drow[1];

    for (int it = 0; it < 22; ++it) {       // rounds 0..43 with prefetch
        const float d0n = drow[2 * it + 2];
        const float d1n = drow[2 * it + 3];
        const half8* wn = wq + 512;

        KROUND(d0, pA0, pA1, pA2, pA3);     // even round 2it
        pA0 = wn[0];  pA1 = wn[64];  pA2 = wn[128]; pA3 = wn[192];

        KROUND(d1, pB0, pB1, pB2, pB3);     // odd round 2it+1
        pB0 = wn[256]; pB1 = wn[320]; pB2 = wn[384]; pB3 = wn[448];

        wq = wn;
        d0 = d0n; d1 = d1n;
    }
    KROUND(d0, pA0, pA1, pA2, pA3);         // round 44, no prefetch
    KROUND(d1, pB0, pB1, pB2, pB3);         // round 45
#undef KROUND
#undef XT

    __syncthreads();   // all K-loops done -> dist region reused as red/h1
    float* lds_red = lds_dist;   // 16 KB red region + h1 live inside it

    // ---- kh reduction. C/D: col = lane&31 (+nh*32),
    //      row el = (rg&3) + 8*(rg>>2) + 4*lh ----
    if (wave >= 2) {
        float* dst = lds_red + (wave - 2) * 2048;
#pragma unroll
        for (int rg = 0; rg < 16; ++rg) {
            const int el = (rg & 3) + 8 * (rg >> 2) + 4 * lh;
            dst[el * 64 + m]      = accA[rg];
            dst[el * 64 + 32 + m] = accB[rg];
        }
    }
    __syncthreads();
    if (wave < 2) {
        const float* srcr = lds_red + wave * 2048;
#pragma unroll
        for (int rg = 0; rg < 16; ++rg) {
            const int el = (rg & 3) + 8 * (rg >> 2) + 4 * lh;
            accA[rg] += srcr[el * 64 + m];
            accB[rg] += srcr[el * 64 + 32 + m];
        }
    }
    __syncthreads();
    if (wave == 1) {
#pragma unroll
        for (int rg = 0; rg < 16; ++rg) {
            const int el = (rg & 3) + 8 * (rg >> 2) + 4 * lh;
            lds_red[el * 64 + m]      = accA[rg];
            lds_red[el * 64 + 32 + m] = accB[rg];
        }
    }
    __syncthreads();
    if (wave == 0) {
        const float bA = b1[m], bB = b1[32 + m];
#pragma unroll
        for (int rg = 0; rg < 16; ++rg) {
            const int el = (rg & 3) + 8 * (rg >> 2) + 4 * lh;
            accA[rg] += lds_red[el * 64 + m];
            accB[rg] += lds_red[el * 64 + 32 + m];
        }
        // wave-0 LDS ops are in-order: reads above retire before these writes
#pragma unroll
        for (int rg = 0; rg < 16; ++rg) {
            const int el = (rg & 3) + 8 * (rg >> 2) + 4 * lh;
            lds_red[el * H1LD + m]      = ssp(accA[rg] + bA);
            lds_red[el * H1LD + 32 + m] = ssp(accB[rg] + bB);
        }
    }
    __syncthreads();

    // ---- tail: layers 2/3 (asy already in a register) ----
    const int b_local = tid >> 3;
    const int g       = tid & 7;
    const int b       = blockIdx.x * TB + b_local;
    asy = redg(asy);

    const float4* __restrict__ W2v = (const float4*)W2;
    const float4* __restrict__ b2v = (const float4*)b2;
    const int wbi = g * 2;
    const float4 b2a = b2v[wbi], b2b = b2v[wbi + 1];
    float s0 = b2a.x, s1 = b2a.y, s2 = b2a.z, s3 = b2a.w;
    float s4 = b2b.x, s5 = b2b.y, s6 = b2b.z, s7 = b2b.w;

    const float* __restrict__ h1row = lds_red + b_local * H1LD;
    for (int k = 0; k < HIDDEN; ++k) {
        const float hk  = h1row[k];
        const float4 wa = W2v[k * 16 + wbi];
        const float4 wb = W2v[k * 16 + wbi + 1];
        s0 = fmaf(hk, wa.x, s0); s1 = fmaf(hk, wa.y, s1);
        s2 = fmaf(hk, wa.z, s2); s3 = fmaf(hk, wa.w, s3);
        s4 = fmaf(hk, wb.x, s4); s5 = fmaf(hk, wb.y, s5);
        s6 = fmaf(hk, wb.z, s6); s7 = fmaf(hk, wb.w, s7);
    }

    const float4* __restrict__ W3v = (const float4*)W3;
    const float4 w3a = W3v[wbi], w3b = W3v[wbi + 1];
    float part = ssp(s0) * w3a.x + ssp(s1) * w3a.y
               + ssp(s2) * w3a.z + ssp(s3) * w3a.w
               + ssp(s4) * w3b.x + ssp(s5) * w3b.y
               + ssp(s6) * w3b.z + ssp(s7) * w3b.w;
    part = redg(part);

    if (g == 0) {
        const float ys = part + b3[0];
        out[b] = __expf(ys) * __expf(-asy);
    }
}

extern "C" void kernel_launch(void* const* d_in, const int* in_sizes, int n_in,
                              void* d_out, int out_size, void* d_ws, size_t ws_size,
                              hipStream_t stream) {
    const float* rs      = (const float*)d_in[0];
    const float* coords  = (const float*)d_in[1];
    const float* charges = (const float*)d_in[2];
    const float* W1      = (const float*)d_in[3];
    const float* b1      = (const float*)d_in[4];
    const float* W2      = (const float*)d_in[5];
    const float* b2      = (const float*)d_in[6];
    const float* W3      = (const float*)d_in[7];
    const float* b3      = (const float*)d_in[8];
    float* out = (float*)d_out;

    const int batch = in_sizes[0] / (N_EL * 3);   // 32768
    half8* ws = (half8*)d_ws;                     // 736 KB scratch

    prep_w1_kernel<<<N_PAIRS, 256, 0, stream>>>(W1, ws);
    wfnet_kernel<<<batch / TB, BLOCK, 0, stream>>>(rs, coords, charges, ws,
                                                   b1, W2, b2, W3, b3, out);
}